// Round 2
// baseline (1752.762 us; speedup 1.0000x reference)
//
#include <hip/hip_runtime.h>
#include <hip/hip_bf16.h>
#include <cstdint>
#include <cstddef>

// Problem constants
// o: (96,100,1024)  u: (96,100,2048)  w: (96,30,768)  mask: (96,30)
// Wku: (2048,256) bku: (256)  Wkw: (768,256) bkw  Wfo: (1024,256) bfo  Wfw: (768,256) bfw
// Outputs: loss(1), att(96,96,30,100), att_V_o(96,96,30,256)

// ---------------- GEMM: C[M,256] = A[M,K] @ W[K,256] + bias ----------------
// 64x64 output tile per block, 256 threads, each thread 4x4. K tiled by 16.
__global__ __launch_bounds__(256) void gemm_bias_kernel(
    const float* __restrict__ A, const float* __restrict__ W,
    const float* __restrict__ bias, float* __restrict__ C,
    int M, int K) {
  __shared__ float a_s[64][20];   // +4 pad, rows 16B-aligned (80B stride)
  __shared__ float w_s[16][64];
  const int m0 = blockIdx.x * 64;
  const int n0 = blockIdx.y * 64;
  const int tid = threadIdx.x;
  const int ty = tid >> 4;   // 0..15
  const int tx = tid & 15;   // 0..15
  const int arow = tid >> 2;          // 0..63
  const int akq  = (tid & 3) << 2;    // 0,4,8,12
  const int wkr  = tid >> 4;          // 0..15
  const int wnq  = (tid & 15) << 2;   // 0..60
  float acc[4][4] = {};
  for (int kt = 0; kt < K; kt += 16) {
    float4 av = *reinterpret_cast<const float4*>(&A[(size_t)(m0 + arow) * K + kt + akq]);
    *reinterpret_cast<float4*>(&a_s[arow][akq]) = av;
    float4 wv = *reinterpret_cast<const float4*>(&W[(size_t)(kt + wkr) * 256 + n0 + wnq]);
    *reinterpret_cast<float4*>(&w_s[wkr][wnq]) = wv;
    __syncthreads();
#pragma unroll
    for (int k = 0; k < 16; ++k) {
      const float a0 = a_s[ty * 4 + 0][k];
      const float a1 = a_s[ty * 4 + 1][k];
      const float a2 = a_s[ty * 4 + 2][k];
      const float a3 = a_s[ty * 4 + 3][k];
      const float4 wv2 = *reinterpret_cast<float4*>(&w_s[k][tx * 4]);
      acc[0][0] += a0 * wv2.x; acc[0][1] += a0 * wv2.y; acc[0][2] += a0 * wv2.z; acc[0][3] += a0 * wv2.w;
      acc[1][0] += a1 * wv2.x; acc[1][1] += a1 * wv2.y; acc[1][2] += a1 * wv2.z; acc[1][3] += a1 * wv2.w;
      acc[2][0] += a2 * wv2.x; acc[2][1] += a2 * wv2.y; acc[2][2] += a2 * wv2.z; acc[2][3] += a2 * wv2.w;
      acc[3][0] += a3 * wv2.x; acc[3][1] += a3 * wv2.y; acc[3][2] += a3 * wv2.z; acc[3][3] += a3 * wv2.w;
    }
    __syncthreads();
  }
  const float4 bv = *reinterpret_cast<const float4*>(&bias[n0 + tx * 4]);
#pragma unroll
  for (int i = 0; i < 4; ++i) {
    const int row = m0 + ty * 4 + i;
    float4 r;
    r.x = acc[i][0] + bv.x;
    r.y = acc[i][1] + bv.y;
    r.z = acc[i][2] + bv.z;
    r.w = acc[i][3] + bv.w;
    *reinterpret_cast<float4*>(&C[(size_t)row * 256 + n0 + tx * 4]) = r;
  }
}

// ---------------- Fused attention core ----------------
// One block per (b, w) pair. 256 threads: ty = tid/32 (8), tx = tid%32 (32).
// Phase 1: S[t][o] = (1/16) * sum_k Kw[w,t,k]*Ku[b,o,k], t<30 (padded 32), o<100 (padded 128)
//   thread micro-tile: t = ty*4+i (i<4), o = tx+32*j (j<4)
// Softmax over o per row t (shfl_xor across the 32-lane tx group).
// Phase 2: att_V_o[t][d] = sum_o att[t][o]*Vo[b,o,d]; logits[w,b,t] = sum_d avo*Vw[w,t,d]
__global__ __launch_bounds__(256) void fused_att_kernel(
    const float* __restrict__ Kw, const float* __restrict__ Ku,
    const float* __restrict__ Vo, const float* __restrict__ Vw,
    float* __restrict__ att_out, float* __restrict__ avo_out,
    float* __restrict__ logits) {
  const int b = blockIdx.x;  // 0..95
  const int w = blockIdx.y;  // 0..95
  __shared__ float kw_s[32][68];    // 8704 B
  __shared__ float big_s[100][68];  // 27200 B (Ku chunk, then Vo chunk)
  __shared__ float s_s[32][104];    // 13312 B (att rows)
  const int tid = threadIdx.x;
  const int ty = tid >> 5;  // 0..7
  const int tx = tid & 31;  // 0..31

  float acc[4][4] = {};
  for (int kc = 0; kc < 4; ++kc) {
    // stage Kw chunk: rows 0..29 real, 30..31 zero
    for (int idx = tid; idx < 512; idx += 256) {
      const int t = idx >> 4;
      const int kq = (idx & 15) << 2;
      float4 v = make_float4(0.f, 0.f, 0.f, 0.f);
      if (t < 30)
        v = *reinterpret_cast<const float4*>(&Kw[(size_t)((w * 30 + t) << 8) + kc * 64 + kq]);
      *reinterpret_cast<float4*>(&kw_s[t][kq]) = v;
    }
    // stage Ku chunk: 100 x 64
    for (int idx = tid; idx < 1600; idx += 256) {
      const int o = idx >> 4;
      const int kq = (idx & 15) << 2;
      *reinterpret_cast<float4*>(&big_s[o][kq]) =
          *reinterpret_cast<const float4*>(&Ku[(size_t)((b * 100 + o) << 8) + kc * 64 + kq]);
    }
    __syncthreads();
#pragma unroll 4
    for (int k = 0; k < 64; k += 4) {
      float4 kwv[4];
#pragma unroll
      for (int i = 0; i < 4; ++i)
        kwv[i] = *reinterpret_cast<float4*>(&kw_s[ty * 4 + i][k]);
      float4 kuv[4];
#pragma unroll
      for (int j = 0; j < 4; ++j) {
        const int o = tx + 32 * j;
        kuv[j] = (o < 100) ? *reinterpret_cast<float4*>(&big_s[o][k])
                           : make_float4(0.f, 0.f, 0.f, 0.f);
      }
#pragma unroll
      for (int i = 0; i < 4; ++i) {
        const float ka[4] = {kwv[i].x, kwv[i].y, kwv[i].z, kwv[i].w};
#pragma unroll
        for (int j = 0; j < 4; ++j) {
          const float ua[4] = {kuv[j].x, kuv[j].y, kuv[j].z, kuv[j].w};
          acc[i][j] += ka[0] * ua[0] + ka[1] * ua[1] + ka[2] * ua[2] + ka[3] * ua[3];
        }
      }
    }
    __syncthreads();
  }

  // softmax over o per row
  const bool v3 = (tx < 4);  // j==3 lane validity (o = tx+96 < 100)
  float att_r[4][4];
#pragma unroll
  for (int i = 0; i < 4; ++i) {
    float m = -1e30f;
#pragma unroll
    for (int j = 0; j < 4; ++j) {
      const float s = acc[i][j] * 0.0625f;  // 1/sqrt(256)
      acc[i][j] = s;
      if (j < 3 || v3) m = fmaxf(m, s);
    }
#pragma unroll
    for (int dm = 16; dm; dm >>= 1) m = fmaxf(m, __shfl_xor(m, dm));
    float l = 0.f;
#pragma unroll
    for (int j = 0; j < 4; ++j) {
      const float p = (j < 3 || v3) ? __expf(acc[i][j] - m) : 0.f;
      att_r[i][j] = p;
      l += p;
    }
#pragma unroll
    for (int dm = 16; dm; dm >>= 1) l += __shfl_xor(l, dm);
    const float inv = 1.f / l;
#pragma unroll
    for (int j = 0; j < 4; ++j) att_r[i][j] *= inv;
  }

  // store att to LDS + global
#pragma unroll
  for (int i = 0; i < 4; ++i) {
    const int t = ty * 4 + i;
#pragma unroll
    for (int j = 0; j < 4; ++j) {
      const int o = tx + 32 * j;
      if (o < 100) {
        s_s[t][o] = att_r[i][j];
        if (t < 30)
          att_out[(size_t)((w * 96 + b) * 30 + t) * 100 + o] = att_r[i][j];
      }
    }
  }

  // Phase 2: PV + logits
  float logit_part[4] = {0.f, 0.f, 0.f, 0.f};
  for (int dc = 0; dc < 4; ++dc) {
    __syncthreads();  // big_s free (QK reads / previous chunk done)
    for (int idx = tid; idx < 1600; idx += 256) {
      const int o = idx >> 4;
      const int dq = (idx & 15) << 2;
      *reinterpret_cast<float4*>(&big_s[o][dq]) =
          *reinterpret_cast<const float4*>(&Vo[(size_t)((b * 100 + o) << 8) + dc * 64 + dq]);
    }
    __syncthreads();
    float acc2[4][2] = {};
    for (int oq = 0; oq < 100; oq += 4) {
      const float4 sa0 = *reinterpret_cast<float4*>(&s_s[ty * 4 + 0][oq]);
      const float4 sa1 = *reinterpret_cast<float4*>(&s_s[ty * 4 + 1][oq]);
      const float4 sa2 = *reinterpret_cast<float4*>(&s_s[ty * 4 + 2][oq]);
      const float4 sa3 = *reinterpret_cast<float4*>(&s_s[ty * 4 + 3][oq]);
      const float a0[4] = {sa0.x, sa0.y, sa0.z, sa0.w};
      const float a1[4] = {sa1.x, sa1.y, sa1.z, sa1.w};
      const float a2[4] = {sa2.x, sa2.y, sa2.z, sa2.w};
      const float a3[4] = {sa3.x, sa3.y, sa3.z, sa3.w};
#pragma unroll
      for (int u2 = 0; u2 < 4; ++u2) {
        const float v0 = big_s[oq + u2][tx];
        const float v1 = big_s[oq + u2][tx + 32];
        acc2[0][0] += a0[u2] * v0; acc2[0][1] += a0[u2] * v1;
        acc2[1][0] += a1[u2] * v0; acc2[1][1] += a1[u2] * v1;
        acc2[2][0] += a2[u2] * v0; acc2[2][1] += a2[u2] * v1;
        acc2[3][0] += a3[u2] * v0; acc2[3][1] += a3[u2] * v1;
      }
    }
#pragma unroll
    for (int i = 0; i < 4; ++i) {
      const int t = ty * 4 + i;
      if (t >= 30) continue;
#pragma unroll
      for (int jj = 0; jj < 2; ++jj) {
        const int d = dc * 64 + tx + 32 * jj;
        const float val = acc2[i][jj];
        avo_out[(size_t)((w * 96 + b) * 30 + t) * 256 + d] = val;
        logit_part[i] += val * Vw[(size_t)((w * 30 + t) << 8) + d];
      }
    }
  }
#pragma unroll
  for (int i = 0; i < 4; ++i) {
    float lp = logit_part[i];
#pragma unroll
    for (int dm = 16; dm; dm >>= 1) lp += __shfl_xor(lp, dm);
    const int t = ty * 4 + i;
    if (tx == 0 && t < 30)
      logits[(size_t)(w * 96 + b) * 30 + t] = lp;
  }
}

// ---------------- Loss ----------------
// block per w (96 blocks, 128 threads). For each t: LSE over b of logits[w,b,t].
__global__ __launch_bounds__(128) void loss_kernel(
    const float* __restrict__ logits, const float* __restrict__ mask,
    float* __restrict__ loss_acc) {
  const int w = blockIdx.x;
  const int b = threadIdx.x;  // 0..127
  __shared__ float red[128];
  float acc = 0.f;
  float nnm = 0.f;
  for (int t = 0; t < 30; ++t) {
    const float v = (b < 96) ? logits[(size_t)(w * 96 + b) * 30 + t] : -1e30f;
    red[b] = v;
    __syncthreads();
    for (int s = 64; s; s >>= 1) {
      if (b < s) red[b] = fmaxf(red[b], red[b + s]);
      __syncthreads();
    }
    const float mx = red[0];
    __syncthreads();
    red[b] = (b < 96) ? __expf(v - mx) : 0.f;
    __syncthreads();
    for (int s = 64; s; s >>= 1) {
      if (b < s) red[b] += red[b + s];
      __syncthreads();
    }
    const float lse = mx + __logf(red[0]);
    __syncthreads();
    if (b == 0) {
      const float diag = logits[(size_t)(w * 96 + w) * 30 + t];
      const float mval = mask[w * 30 + t];
      acc += (1.f - mval) * (diag - lse);
      nnm += (1.f - mval);
    }
  }
  if (b == 0) atomicAdd(loss_acc, acc / (nnm + 1e-6f));
}

__global__ void finalize_kernel(const float* __restrict__ loss_acc,
                                float* __restrict__ out) {
  out[0] = -loss_acc[0] * (1.f / 96.f);
}

// ---------------- Launch ----------------
extern "C" void kernel_launch(void* const* d_in, const int* in_sizes, int n_in,
                              void* d_out, int out_size, void* d_ws, size_t ws_size,
                              hipStream_t stream) {
  const float* o_in  = (const float*)d_in[0];
  const float* u_in  = (const float*)d_in[1];
  const float* w_in  = (const float*)d_in[2];
  const float* mask  = (const float*)d_in[3];
  const float* Wku   = (const float*)d_in[4];
  const float* bku   = (const float*)d_in[5];
  const float* Wkw   = (const float*)d_in[6];
  const float* bkw   = (const float*)d_in[7];
  const float* Wfo   = (const float*)d_in[8];
  const float* bfo   = (const float*)d_in[9];
  const float* Wfw   = (const float*)d_in[10];
  const float* bfw   = (const float*)d_in[11];
  float* out = (float*)d_out;
  float* ws = (float*)d_ws;

  // workspace layout (floats)
  float* Ku     = ws;                   // 9600*256 = 2,457,600
  float* Vo     = Ku + 2457600;         // 2,457,600
  float* Kw     = Vo + 2457600;         // 2880*256 = 737,280
  float* Vw     = Kw + 737280;          // 737,280
  float* logits = Vw + 737280;          // 96*96*30 = 276,480
  float* lacc   = logits + 276480;      // 1

  hipMemsetAsync(lacc, 0, sizeof(float), stream);

  dim3 blk(256);
  gemm_bias_kernel<<<dim3(9600 / 64, 4), blk, 0, stream>>>(u_in, Wku, bku, Ku, 9600, 2048);
  gemm_bias_kernel<<<dim3(2880 / 64, 4), blk, 0, stream>>>(w_in, Wkw, bkw, Kw, 2880, 768);
  gemm_bias_kernel<<<dim3(9600 / 64, 4), blk, 0, stream>>>(o_in, Wfo, bfo, Vo, 9600, 1024);
  gemm_bias_kernel<<<dim3(2880 / 64, 4), blk, 0, stream>>>(w_in, Wfw, bfw, Vw, 2880, 768);

  float* att_out = out + 1;
  float* avo_out = out + 1 + (size_t)96 * 96 * 30 * 100;
  fused_att_kernel<<<dim3(96, 96), blk, 0, stream>>>(Kw, Ku, Vo, Vw, att_out, avo_out, logits);

  loss_kernel<<<dim3(96), dim3(128), 0, stream>>>(logits, mask, lacc);
  finalize_kernel<<<1, 1, 0, stream>>>(lacc, out);
}